// Round 1
// baseline (171.707 us; speedup 1.0000x reference)
//
#include <hip/hip_runtime.h>
#include <hip/hip_bf16.h>
#include <math.h>

// ThickCubeSimulator: fused disk-model spectral cube + pooling.
// Grid: one block per coarse output pixel (80x80 = 6400 blocks).
// Block: 640 threads = 4 fine pixels x 160 fine channels (10 waves).

#define NFINE 160   // fine spatial resolution (z cells and fine pixels per axis)
#define FFINE 160   // fine frequency channels
#define RES   80    // coarse output resolution
#define C_KMS 299792.458f
#define F0GHZ 230.538f
#define LOG2E 1.44269504088896340736f

__device__ __forceinline__ float fast_exp2(float x) {
#if __has_builtin(__builtin_amdgcn_exp2f)
  return __builtin_amdgcn_exp2f(x);
#else
  return exp2f(x);
#endif
}

__global__ __launch_bounds__(640) void thickcube_kernel(
    const float* __restrict__ p_inc, const float* __restrict__ p_rot,
    const float* __restrict__ p_lb,  const float* __restrict__ p_vs,
    const float* __restrict__ p_vmax, const float* __restrict__ p_rturn,
    const float* __restrict__ p_i0,  const float* __restrict__ p_rd,
    const float* __restrict__ freqs, float* __restrict__ out)
{
  __shared__ float4 cell[4 * NFINE];      // per fine pixel x z: (vlos, c2*vlos^2, inten, pad)
  __shared__ float  partial[4 * FFINE];   // per (fine pixel, fine channel) z-sum

  const int t   = threadIdx.x;
  const int blk = blockIdx.x;
  const int p   = blk / RES;      // coarse row (x index)
  const int q   = blk - p * RES;  // coarse col (y index)

  // scalar params (tiny, L2/L3 broadcast)
  const float inc    = p_inc[0];
  const float rot    = p_rot[0];
  const float sig    = p_lb[0];
  const float vshift = p_vs[0];
  const float vmax   = p_vmax[0];
  const float rturn  = p_rturn[0];
  const float i0v    = p_i0[0];
  const float rd     = p_rd[0];
  const float fc0    = freqs[0];
  const float fc1    = freqs[1];

  const float ci = cosf(inc), si = sinf(inc);
  const float cr = cosf(rot), sr = sinf(rot);
  // Gaussian exponent constant with log2(e) folded in: w = exp2(c2 * d^2)
  const float c2 = -0.5f * LOG2E / (sig * sig);

  // ---- phase 1: one cell per thread -> LDS ----
  {
    const int fp = t / NFINE;        // 0..3 fine pixel within 2x2
    const int k  = t - fp * NFINE;   // 0..159 z cell
    const int i  = 2 * p + (fp >> 1);
    const int j  = 2 * q + (fp & 1);
    // fine spatial axis: x0 = -1000 + 0.5*12.5, dx = 12.5
    const float gx = -993.75f + 12.5f * (float)i;
    const float gy = -993.75f + 12.5f * (float)j;
    const float gz = -993.75f + 12.5f * (float)k;
    // Rz(sky_rot) then Rx(inclination)
    const float x1 = gx * cr - gy * sr;
    const float y1 = gx * sr + gy * cr;
    const float rx = x1;
    const float ry = y1 * ci - gz * si;
    const float rz = y1 * si + gz * ci;
    const float r2xy = rx * rx + ry * ry;
    const float rsph = sqrtf(r2xy + rz * rz);
    const float inten = i0v * __expf(-rsph / rd);
    const float rcyl = sqrtf(r2xy);
    // v_abs = vmax * (2/pi) * atan(rcyl/rturn); cos(atan2(ry,rx)) = rx/rcyl
    const float vabs = vmax * 0.63661977236758134308f * atanf(rcyl / rturn);
    const float cosT = rx / fmaxf(rcyl, 1e-20f);
    const float vlos = -vabs * cosT * si;
    cell[fp * NFINE + k] = make_float4(vlos, c2 * vlos * vlos, inten, 0.0f);
  }
  __syncthreads();

  // ---- phase 2: thread <-> (fine pixel, fine channel); sum over z ----
  const int fp = t / FFINE;
  const int m  = t - fp * FFINE;
  const float df    = (fc1 - fc0) * 0.25f;         // df_c / FREQ_UP
  const float f0    = fc0 - 1.5f * df;             // fc0 - (FREQ_UP-1)*df/2
  const float ffine = f0 + df * (float)m;
  const float vlab  = C_KMS * (F0GHZ - ffine) / F0GHZ - vshift;
  // arg = c2*(vlab - vlos)^2 = (a + c2*vlos^2) + b*vlos
  const float a = c2 * vlab * vlab;
  const float b = -2.0f * c2 * vlab;

  const float4* crow = &cell[fp * NFINE];
  float acc0 = 0.f, acc1 = 0.f, acc2 = 0.f, acc3 = 0.f;
  for (int k = 0; k < NFINE; k += 4) {
    const float4 c0 = crow[k + 0];
    const float4 c1 = crow[k + 1];
    const float4 cc = crow[k + 2];
    const float4 c3 = crow[k + 3];
    acc0 = fmaf(fast_exp2(fmaf(b, c0.x, a + c0.y)), c0.z, acc0);
    acc1 = fmaf(fast_exp2(fmaf(b, c1.x, a + c1.y)), c1.z, acc1);
    acc2 = fmaf(fast_exp2(fmaf(b, cc.x, a + cc.y)), cc.z, acc2);
    acc3 = fmaf(fast_exp2(fmaf(b, c3.x, a + c3.y)), c3.z, acc3);
  }
  partial[t] = (acc0 + acc1) + (acc2 + acc3);
  __syncthreads();

  // ---- phase 3: pool 4 fine channels x 2x2 fine pixels -> one coarse value ----
  if (t < 40) {
    float s = 0.f;
    #pragma unroll
    for (int fpp = 0; fpp < 4; ++fpp) {
      #pragma unroll
      for (int dm = 0; dm < 4; ++dm) {
        s += partial[fpp * FFINE + 4 * t + dm];
      }
    }
    const float norm = 0.3989422804014327f / sig;  // 1/sqrt(2*pi*sig^2)
    out[t * (RES * RES) + p * RES + q] = s * norm * 0.0625f;
  }
}

extern "C" void kernel_launch(void* const* d_in, const int* in_sizes, int n_in,
                              void* d_out, int out_size, void* d_ws, size_t ws_size,
                              hipStream_t stream) {
  const float* p_inc   = (const float*)d_in[0];
  const float* p_rot   = (const float*)d_in[1];
  const float* p_lb    = (const float*)d_in[2];
  const float* p_vs    = (const float*)d_in[3];
  const float* p_vmax  = (const float*)d_in[4];
  const float* p_rturn = (const float*)d_in[5];
  const float* p_i0    = (const float*)d_in[6];
  const float* p_rd    = (const float*)d_in[7];
  const float* freqs   = (const float*)d_in[8];
  float* out = (float*)d_out;

  dim3 grid(RES * RES);   // 6400 blocks, one per coarse pixel
  dim3 block(4 * FFINE);  // 640 threads
  hipLaunchKernelGGL(thickcube_kernel, grid, block, 0, stream,
                     p_inc, p_rot, p_lb, p_vs, p_vmax, p_rturn, p_i0, p_rd,
                     freqs, out);
}

// Round 2
// 123.536 us; speedup vs baseline: 1.3899x; 1.3899x over previous
//
#include <hip/hip_runtime.h>
#include <hip/hip_bf16.h>
#include <math.h>

// ThickCubeSimulator: fused disk-model spectral cube + pooling.
// Grid: one block per coarse output pixel (80x80 = 6400 blocks), 640 threads.
// R1: LDS-pipe was the bottleneck (10.24M ds_read_b128 ~= 200us ~= measured 188us).
//     -> fold intensity into exponent (8 B/cell), 4 fine channels per thread:
//        each ds_read_b128 now feeds 2 cells x 4 channels = 8 exps (was 1).

#define NFINE 160   // fine spatial resolution (z cells; fine pixels per axis = 160)
#define FFINE 160   // fine frequency channels
#define RES   80    // coarse output resolution
#define C_KMS 299792.458f
#define F0GHZ 230.538f
#define LOG2E 1.44269504088896340736f

__device__ __forceinline__ float fast_exp2(float x) {
#if __has_builtin(__builtin_amdgcn_exp2f)
  return __builtin_amdgcn_exp2f(x);
#else
  return exp2f(x);
#endif
}

__global__ __launch_bounds__(640) void thickcube_kernel(
    const float* __restrict__ p_inc, const float* __restrict__ p_rot,
    const float* __restrict__ p_lb,  const float* __restrict__ p_vs,
    const float* __restrict__ p_vmax, const float* __restrict__ p_rturn,
    const float* __restrict__ p_i0,  const float* __restrict__ p_rd,
    const float* __restrict__ freqs, float* __restrict__ out)
{
  // per cell: (vlos, A) with A = c2*vlos^2 + log2(intensity)
  __shared__ __align__(16) float2 cell[4 * NFINE];   // 5120 B
  __shared__ float partial[640];                     // 2560 B

  const int t   = threadIdx.x;
  const int blk = blockIdx.x;
  const int p   = blk / RES;      // coarse row (x index)
  const int q   = blk - p * RES;  // coarse col (y index)

  const float inc    = p_inc[0];
  const float rot    = p_rot[0];
  const float sig    = p_lb[0];
  const float vshift = p_vs[0];
  const float vmax   = p_vmax[0];
  const float rturn  = p_rturn[0];
  const float i0v    = p_i0[0];
  const float rd     = p_rd[0];
  const float fc0    = freqs[0];
  const float fc1    = freqs[1];

  const float ci = cosf(inc), si = sinf(inc);
  const float cr = cosf(rot), sr = sinf(rot);
  // Gaussian exponent constant with log2(e) folded in: w = exp2(c2 * d^2)
  const float c2 = -0.5f * LOG2E / (sig * sig);

  // ---- phase 1: one cell per thread -> LDS (vlos, A) ----
  {
    const int fp = t / NFINE;        // 0..3 fine pixel within 2x2
    const int k  = t - fp * NFINE;   // 0..159 z cell
    const int i  = 2 * p + (fp >> 1);
    const int j  = 2 * q + (fp & 1);
    const float gx = -993.75f + 12.5f * (float)i;
    const float gy = -993.75f + 12.5f * (float)j;
    const float gz = -993.75f + 12.5f * (float)k;
    const float x1 = gx * cr - gy * sr;
    const float y1 = gx * sr + gy * cr;
    const float rx = x1;
    const float ry = y1 * ci - gz * si;
    const float rz = y1 * si + gz * ci;
    const float r2xy = rx * rx + ry * ry;
    const float rsph = sqrtf(r2xy + rz * rz);
    // log2(intensity) = log2(i0) - (rsph/rd)*log2(e)   (no exp needed)
    const float loginten = __log2f(i0v) - rsph * (LOG2E / rd);
    const float rcyl = sqrtf(r2xy);
    const float vabs = vmax * 0.63661977236758134308f * atanf(rcyl / rturn);
    const float cosT = rx / fmaxf(rcyl, 1e-20f);
    const float vlos = -vabs * cosT * si;
    cell[fp * NFINE + k] = make_float2(vlos, fmaf(c2 * vlos, vlos, loginten));
  }
  __syncthreads();

  // ---- phase 2: thread = (fine pixel, z-chunk, coarse channel) ----
  // t = ((fp*4 + zc)*40 + m4); lanes 0..39 share one cell address (broadcast),
  // lanes 40..63 a second -> 2 distinct LDS addresses per wave read (free).
  const int m4 = t % 40;          // coarse channel
  const int g  = t / 40;          // 0..15
  const int fp2 = g >> 2;         // fine pixel
  const int zc  = g & 3;          // z chunk (40 cells)

  const float df = (fc1 - fc0) * 0.25f;
  const float f0 = fc0 - 1.5f * df;
  float a[4], b[4];
  #pragma unroll
  for (int r = 0; r < 4; ++r) {
    const int m = m4 * 4 + r;                    // fine channel
    const float ffine = f0 + df * (float)m;
    const float vlab  = C_KMS * (F0GHZ - ffine) / F0GHZ - vshift;
    a[r] = c2 * vlab * vlab;
    b[r] = -2.0f * c2 * vlab;
  }

  const float4* crow = (const float4*)&cell[fp2 * NFINE + zc * 40];
  float acc0 = 0.f, acc1 = 0.f, acc2 = 0.f, acc3 = 0.f;
  #pragma unroll 4
  for (int c = 0; c < 20; ++c) {
    const float4 v = crow[c];     // cells 2c, 2c+1: (vlos0, A0, vlos1, A1)
    acc0 += fast_exp2(fmaf(b[0], v.x, a[0] + v.y));
    acc1 += fast_exp2(fmaf(b[1], v.x, a[1] + v.y));
    acc2 += fast_exp2(fmaf(b[2], v.x, a[2] + v.y));
    acc3 += fast_exp2(fmaf(b[3], v.x, a[3] + v.y));
    acc0 += fast_exp2(fmaf(b[0], v.z, a[0] + v.w));
    acc1 += fast_exp2(fmaf(b[1], v.z, a[1] + v.w));
    acc2 += fast_exp2(fmaf(b[2], v.z, a[2] + v.w));
    acc3 += fast_exp2(fmaf(b[3], v.z, a[3] + v.w));
  }
  // the 4 fine channels of this thread all pool into coarse channel m4
  partial[t] = (acc0 + acc1) + (acc2 + acc3);
  __syncthreads();

  // ---- phase 3: sum 16 partials (4 fp x 4 zc) per coarse channel ----
  if (t < 40) {
    float s = 0.f;
    #pragma unroll
    for (int gg = 0; gg < 16; ++gg) s += partial[gg * 40 + t];
    const float norm = 0.3989422804014327f / sig;  // 1/sqrt(2*pi*sig^2)
    out[t * (RES * RES) + p * RES + q] = s * norm * 0.0625f;
  }
}

extern "C" void kernel_launch(void* const* d_in, const int* in_sizes, int n_in,
                              void* d_out, int out_size, void* d_ws, size_t ws_size,
                              hipStream_t stream) {
  const float* p_inc   = (const float*)d_in[0];
  const float* p_rot   = (const float*)d_in[1];
  const float* p_lb    = (const float*)d_in[2];
  const float* p_vs    = (const float*)d_in[3];
  const float* p_vmax  = (const float*)d_in[4];
  const float* p_rturn = (const float*)d_in[5];
  const float* p_i0    = (const float*)d_in[6];
  const float* p_rd    = (const float*)d_in[7];
  const float* freqs   = (const float*)d_in[8];
  float* out = (float*)d_out;

  dim3 grid(RES * RES);   // 6400 blocks, one per coarse pixel
  dim3 block(4 * FFINE);  // 640 threads
  hipLaunchKernelGGL(thickcube_kernel, grid, block, 0, stream,
                     p_inc, p_rot, p_lb, p_vs, p_vmax, p_rturn, p_i0, p_rd,
                     freqs, out);
}

// Round 3
// 89.242 us; speedup vs baseline: 1.9241x; 1.3843x over previous
//
#include <hip/hip_runtime.h>
#include <hip/hip_bf16.h>
#include <math.h>

// ThickCubeSimulator R2: histogram-convolution reformulation.
// Per coarse pixel: S_M = sum_b G[M,b] * H[b], where H = CIC deposit of cell
// intensities binned by v_los (linear in I, so 2x2 spatial pooling folds into
// one histogram; frequency pooling folds into the G table).
// Work: 655M exps -> ~45M; LDS-pipe pressure gone.
// Block = 256 threads, PIX=4 coarse pixels per block -> 1600 blocks.

#define NFINE 160   // fine z cells per column
#define RES   80    // coarse output resolution
#define NB    160   // velocity histogram bins
#define NM    40    // coarse channels
#define PIX   4     // coarse pixels per block
#define VBIN0 -198.75f
#define VBINW 2.5f
#define C_KMS 299792.458f
#define F0GHZ 230.538f
#define LOG2E 1.44269504088896340736f

__device__ __forceinline__ float fast_exp2(float x) {
#if __has_builtin(__builtin_amdgcn_exp2f)
  return __builtin_amdgcn_exp2f(x);
#else
  return exp2f(x);
#endif
}

__global__ __launch_bounds__(256) void thickcube_kernel(
    const float* __restrict__ p_inc, const float* __restrict__ p_rot,
    const float* __restrict__ p_lb,  const float* __restrict__ p_vs,
    const float* __restrict__ p_vmax, const float* __restrict__ p_rturn,
    const float* __restrict__ p_i0,  const float* __restrict__ p_rd,
    const float* __restrict__ freqs, float* __restrict__ out)
{
  __shared__ float Gl[NB * NM];   // 25600 B, layout [bin][channel]
  __shared__ float H[PIX][NB];    // 2560 B

  const int t   = threadIdx.x;
  const int blk = blockIdx.x;          // 0..1599
  const int p   = blk / (RES / PIX);   // coarse row
  const int q0  = (blk - p * (RES / PIX)) * PIX;

  const float inc    = p_inc[0];
  const float rot    = p_rot[0];
  const float sig    = p_lb[0];
  const float vshift = p_vs[0];
  const float vmax   = p_vmax[0];
  const float rturn  = p_rturn[0];
  const float i0v    = p_i0[0];
  const float rd     = p_rd[0];
  const float fc0    = freqs[0];
  const float fc1    = freqs[1];

  const float ci = cosf(inc), si = sinf(inc);
  const float cr = cosf(rot), sr = sinf(rot);
  const float c2l    = -0.5f * LOG2E / (sig * sig);       // exp2-based Gaussian
  const float norm16 = 0.3989422804014327f / sig * 0.0625f; // norm * 1/16 pooling
  const float df = (fc1 - fc0) * 0.25f;
  const float f0 = fc0 - 1.5f * df;

  // ---- zero histograms ----
  for (int e = t; e < PIX * NB; e += 256) ((float*)H)[e] = 0.f;

  // ---- G table: Gl[b*NM+M] = norm16 * sum_{r<4} exp2(c2l*(vlab_{4M+r}-vbin_b)^2)
  for (int e = t; e < NB * NM; e += 256) {
    const int b = e / NM;
    const int M = e - b * NM;
    const float vbin = VBIN0 + VBINW * (float)b;
    float s = 0.f;
    #pragma unroll
    for (int r = 0; r < 4; ++r) {
      const float ffine = f0 + df * (float)(4 * M + r);
      const float vlab  = C_KMS * (F0GHZ - ffine) / F0GHZ - vshift;
      const float d = vlab - vbin;
      s += fast_exp2(c2l * d * d);
    }
    Gl[e] = s * norm16;
  }
  __syncthreads();

  // ---- deposit: PIX pixels x 4 fine pixels x 160 z cells = 2560 cells ----
  for (int c = t; c < PIX * 4 * NFINE; c += 256) {
    const int k  = c % NFINE;
    const int cf = c / NFINE;    // 0..15
    const int fp = cf & 3;       // fine pixel within 2x2
    const int v  = cf >> 2;      // which coarse pixel of this block
    const int i  = 2 * p + (fp >> 1);
    const int j  = 2 * (q0 + v) + (fp & 1);
    const float gx = -993.75f + 12.5f * (float)i;
    const float gy = -993.75f + 12.5f * (float)j;
    const float gz = -993.75f + 12.5f * (float)k;
    // rotated in-plane coords (z of source frame not needed: |r|=|g|)
    const float x1 = gx * cr - gy * sr;
    const float y1 = gx * sr + gy * cr;
    const float ry = y1 * ci - gz * si;
    const float rcyl = sqrtf(x1 * x1 + ry * ry);
    const float vabs = vmax * 0.63661977236758134308f * atanf(rcyl / rturn);
    const float vlos = -vabs * si * x1 / fmaxf(rcyl, 1e-20f);
    const float rsph = sqrtf(gx * gx + gy * gy + gz * gz);
    const float inten = i0v * fast_exp2(-rsph * (LOG2E / rd));
    // CIC deposit into H[v]
    const float u  = fmaf(vlos, 1.0f / VBINW, -VBIN0 / VBINW);  // 0.4*v + 79.5
    const float bf = floorf(u);
    int bidx = (int)bf;
    float fr = u - bf;
    if (bidx < 0)      { bidx = 0;      fr = 0.f; }
    if (bidx > NB - 2) { bidx = NB - 2; fr = 1.f; }
    atomicAdd(&H[v][bidx],     inten * (1.f - fr));
    atomicAdd(&H[v][bidx + 1], inten * fr);
  }
  __syncthreads();

  // ---- matvec: out[M, p, q0+v] = sum_b H[v][b] * Gl[b][M] ----
  if (t < PIX * NM) {
    const int M = t >> 2;   // lanes grouped so stores are 4-consecutive
    const int v = t & 3;
    float acc = 0.f;
    #pragma unroll 8
    for (int b = 0; b < NB; ++b)
      acc = fmaf(H[v][b], Gl[b * NM + M], acc);
    out[M * (RES * RES) + p * RES + (q0 + v)] = acc;
  }
}

extern "C" void kernel_launch(void* const* d_in, const int* in_sizes, int n_in,
                              void* d_out, int out_size, void* d_ws, size_t ws_size,
                              hipStream_t stream) {
  const float* p_inc   = (const float*)d_in[0];
  const float* p_rot   = (const float*)d_in[1];
  const float* p_lb    = (const float*)d_in[2];
  const float* p_vs    = (const float*)d_in[3];
  const float* p_vmax  = (const float*)d_in[4];
  const float* p_rturn = (const float*)d_in[5];
  const float* p_i0    = (const float*)d_in[6];
  const float* p_rd    = (const float*)d_in[7];
  const float* freqs   = (const float*)d_in[8];
  float* out = (float*)d_out;

  dim3 grid((RES / PIX) * RES);   // 1600 blocks, 4 coarse pixels each
  dim3 block(256);
  hipLaunchKernelGGL(thickcube_kernel, grid, block, 0, stream,
                     p_inc, p_rot, p_lb, p_vs, p_vmax, p_rturn, p_i0, p_rd,
                     freqs, out);
}

// Round 4
// 64.481 us; speedup vs baseline: 2.6629x; 1.3840x over previous
//
#include <hip/hip_runtime.h>
#include <hip/hip_bf16.h>
#include <math.h>

// ThickCubeSimulator R3: histogram-convolution with
//  - block-invariant Gaussian table hoisted to a pre-kernel (d_ws)
//  - column-private sub-histograms + ds_add_f32 (unsafeAtomicAdd) deposit
//  - lane mapping spreading a wave over 16 columns x stride-5 z to kill
//    same-address RMW serialization (R2's hidden cost).

#define NFINE 160   // fine z cells per column
#define RES   80    // coarse output resolution
#define NB    160   // velocity histogram bins
#define NBP   161   // padded sub-histogram stride (bank spread)
#define NM    40    // coarse channels
#define GTP   164   // padded G row stride ([M][b], float4-aligned)
#define PIX   4     // coarse pixels per block
#define VBIN0 -198.75f
#define VBINW 2.5f
#define C_KMS 299792.458f
#define F0GHZ 230.538f
#define LOG2E 1.44269504088896340736f

__device__ __forceinline__ float fast_exp2(float x) {
#if __has_builtin(__builtin_amdgcn_exp2f)
  return __builtin_amdgcn_exp2f(x);
#else
  return exp2f(x);
#endif
}

// ---- pre-kernel: GT[M][b] = norm/16 * sum_{r<4} exp2(c2l*(vlab_{4M+r}-vbin_b)^2)
__global__ __launch_bounds__(256) void gtable_kernel(
    const float* __restrict__ p_lb, const float* __restrict__ p_vs,
    const float* __restrict__ freqs, float* __restrict__ gt)
{
  const int e = blockIdx.x * 256 + threadIdx.x;
  if (e >= NM * NB) return;
  const int M = e / NB;
  const int b = e - M * NB;
  const float sig    = p_lb[0];
  const float vshift = p_vs[0];
  const float fc0    = freqs[0];
  const float fc1    = freqs[1];
  const float c2l    = -0.5f * LOG2E / (sig * sig);
  const float norm16 = 0.3989422804014327f / sig * 0.0625f;
  const float df = (fc1 - fc0) * 0.25f;
  const float f0 = fc0 - 1.5f * df;
  const float vbin = VBIN0 + VBINW * (float)b;
  float s = 0.f;
  #pragma unroll
  for (int r = 0; r < 4; ++r) {
    const float ffine = f0 + df * (float)(4 * M + r);
    const float vlab  = C_KMS * (F0GHZ - ffine) / F0GHZ - vshift;
    const float d = vlab - vbin;
    s += fast_exp2(c2l * d * d);
  }
  gt[M * GTP + b] = s * norm16;
}

__global__ __launch_bounds__(512) void thickcube_kernel(
    const float* __restrict__ p_inc, const float* __restrict__ p_rot,
    const float* __restrict__ p_vmax, const float* __restrict__ p_rturn,
    const float* __restrict__ p_i0,  const float* __restrict__ p_rd,
    const float* __restrict__ gt, float* __restrict__ out)
{
  __shared__ __align__(16) float GT[NM * GTP];   // 26240 B
  __shared__ float H16[16 * NBP];                // 10304 B (column-private hists)
  __shared__ __align__(16) float H4[PIX * GTP];  //  2624 B

  const int t   = threadIdx.x;
  const int blk = blockIdx.x;          // 0..1599
  const int p   = blk / (RES / PIX);   // coarse row
  const int q0  = (blk - p * (RES / PIX)) * PIX;

  const float inc   = p_inc[0];
  const float rot   = p_rot[0];
  const float vmax  = p_vmax[0];
  const float rturn = p_rturn[0];
  const float i0v   = p_i0[0];
  const float rd    = p_rd[0];

  const float ci = cosf(inc), si = sinf(inc);
  const float cr = cosf(rot), sr = sinf(rot);

  // ---- stage GT from L2 (issue loads first), zero sub-histograms ----
  for (int e = t; e < NM * GTP / 4; e += 512)
    ((float4*)GT)[e] = ((const float4*)gt)[e];
  for (int e = t; e < 16 * NBP; e += 512) H16[e] = 0.f;
  __syncthreads();

  // ---- deposit: lane = (column 0..15, zbase 0..31), z = zbase*5 + it ----
  {
    const int col = t & 15;    // 16 columns: 4 coarse pixels x 2x2 fine
    const int zb  = t >> 4;    // 0..31
    const int v   = col >> 2;  // coarse pixel
    const int fp  = col & 3;   // fine pixel within 2x2
    const int i   = 2 * p + (fp >> 1);
    const int j   = 2 * (q0 + v) + (fp & 1);
    const float gx = -993.75f + 12.5f * (float)i;
    const float gy = -993.75f + 12.5f * (float)j;
    // column constants (z-independent)
    const float x1 = gx * cr - gy * sr;
    const float y1 = gx * sr + gy * cr;
    const float x12  = x1 * x1;
    const float gxy2 = gx * gx + gy * gy;
    const float kcol = -vmax * 0.63661977236758134308f * si * x1;
    const float irt  = 1.0f / rturn;
    const float crd  = LOG2E / rd;
    float* Hc = &H16[col * NBP];
    #pragma unroll
    for (int it = 0; it < 5; ++it) {
      const int k = zb * 5 + it;          // covers 0..159 exactly once
      const float gz = -993.75f + 12.5f * (float)k;
      const float ry   = y1 * ci - gz * si;
      const float rcyl = sqrtf(fmaf(ry, ry, x12));
      const float atq  = atanf(rcyl * irt);
      const float vlos = kcol * atq / fmaxf(rcyl, 1e-20f);
      const float rsph = sqrtf(fmaf(gz, gz, gxy2));
      const float inten = i0v * fast_exp2(-rsph * crd);
      const float u  = fmaf(vlos, 1.0f / VBINW, -VBIN0 / VBINW);
      const float bf = floorf(u);
      int bidx = (int)bf;
      float fr = u - bf;
      if (bidx < 0)      { bidx = 0;      fr = 0.f; }
      if (bidx > NB - 2) { bidx = NB - 2; fr = 1.f; }
      unsafeAtomicAdd(&Hc[bidx],     inten * (1.f - fr));
      unsafeAtomicAdd(&Hc[bidx + 1], inten * fr);
    }
  }
  __syncthreads();

  // ---- reduce 16 column hists -> 4 coarse-pixel hists ----
  for (int e = t; e < PIX * NB; e += 512) {
    const int v = e / NB;
    const int b = e - v * NB;
    H4[v * GTP + b] = (H16[(4 * v + 0) * NBP + b] + H16[(4 * v + 1) * NBP + b])
                    + (H16[(4 * v + 2) * NBP + b] + H16[(4 * v + 3) * NBP + b]);
  }
  __syncthreads();

  // ---- matvec: out[M, p, q0+v] = sum_b H4[v][b] * GT[M][b] ----
  if (t < PIX * NM) {
    const int M = t >> 2;
    const int v = t & 3;
    const float4* Hv = (const float4*)&H4[v * GTP];
    const float4* Gm = (const float4*)&GT[M * GTP];
    float acc = 0.f;
    #pragma unroll 10
    for (int c = 0; c < NB / 4; ++c) {
      const float4 h = Hv[c];
      const float4 g = Gm[c];
      acc = fmaf(h.x, g.x, acc);
      acc = fmaf(h.y, g.y, acc);
      acc = fmaf(h.z, g.z, acc);
      acc = fmaf(h.w, g.w, acc);
    }
    out[M * (RES * RES) + p * RES + (q0 + v)] = acc;
  }
}

extern "C" void kernel_launch(void* const* d_in, const int* in_sizes, int n_in,
                              void* d_out, int out_size, void* d_ws, size_t ws_size,
                              hipStream_t stream) {
  const float* p_inc   = (const float*)d_in[0];
  const float* p_rot   = (const float*)d_in[1];
  const float* p_lb    = (const float*)d_in[2];
  const float* p_vs    = (const float*)d_in[3];
  const float* p_vmax  = (const float*)d_in[4];
  const float* p_rturn = (const float*)d_in[5];
  const float* p_i0    = (const float*)d_in[6];
  const float* p_rd    = (const float*)d_in[7];
  const float* freqs   = (const float*)d_in[8];
  float* out = (float*)d_out;
  float* gt  = (float*)d_ws;   // NM*GTP floats = 26240 B

  hipLaunchKernelGGL(gtable_kernel, dim3((NM * NB + 255) / 256), dim3(256),
                     0, stream, p_lb, p_vs, freqs, gt);
  hipLaunchKernelGGL(thickcube_kernel, dim3((RES / PIX) * RES), dim3(512),
                     0, stream, p_inc, p_rot, p_vmax, p_rturn, p_i0, p_rd,
                     gt, out);
}